// Round 11
// baseline (346.593 us; speedup 1.0000x reference)
//
#include <hip/hip_runtime.h>
#include <cstdint>
#include <cstddef>

typedef __attribute__((ext_vector_type(8))) _Float16 f16x8;
typedef __attribute__((ext_vector_type(8))) short bf16x8;
typedef __attribute__((ext_vector_type(4))) float f32x4;
typedef __attribute__((ext_vector_type(8))) unsigned short ushort8;

#define CAPF 32768
#define CAP2 32768
// fp16 2-term flag margin (harness-verified in rounds 5, 8, 9, 10)
#define MARGIN2F 4.5e-3f

// packed f32x2 -> bf16x2 (RNE): dst.lo16 = bf16(a), dst.hi16 = bf16(b)
__device__ __forceinline__ unsigned int cvtpk_bf16(float a, float b) {
  unsigned int d;
  asm("v_cvt_pk_bf16_f32 %0, %1, %2" : "=v"(d) : "v"(a), "v"(b));
  return d;
}
__device__ __forceinline__ unsigned short f2h(float f) {
  union { _Float16 h; unsigned short u; } c; c.h = (_Float16)f; return c.u;
}
__device__ __forceinline__ float h2f(unsigned short u) {
  union { unsigned short u; _Float16 h; } c; c.u = u; return (float)c.h;
}
// monotone float -> sortable u32 ordinal
__device__ __forceinline__ unsigned int f2ord(float v) {
  unsigned int s = __float_as_uint(v);
  return s ^ ((unsigned int)((int)s >> 31) | 0x80000000u);
}
__device__ __forceinline__ float ord2f(unsigned int o) {
  unsigned int s = (o & 0x80000000u) ? (o ^ 0x80000000u) : ~o;
  return __uint_as_float(s);
}

// lgkm-only barrier: drains LDS ops but leaves global loads in flight
__device__ __forceinline__ void barrier_lgkm() {
  asm volatile("s_waitcnt lgkmcnt(0)" ::: "memory");
  __builtin_amdgcn_s_barrier();
}

// ---------------------------------------------------------------------------
// kprep: fused {zero Mt + counters, W3->bf16 (cvt_pk), W1->hi/lo fp16, const}
// ---------------------------------------------------------------------------
__global__ __launch_bounds__(256) void kprep(
    float* __restrict__ Mt, int* __restrict__ cntF, int* __restrict__ cnt2,
    const float* __restrict__ W3, unsigned short* __restrict__ W3b,
    const float* __restrict__ W1, unsigned short* __restrict__ w1h,
    unsigned short* __restrict__ w1l,
    const float* __restrict__ b2, const float* __restrict__ b3,
    float* __restrict__ constv) {
  __shared__ float red[4];
  const int bid = blockIdx.x;
  const int t = threadIdx.x;
  if (bid < 512) {
    int e = bid * 256 + t;  // 2 MB of zeros
    ((float4*)Mt)[e] = (float4){0.f, 0.f, 0.f, 0.f};
    if (e == 0) { cntF[0] = 0; cnt2[0] = 0; }
  } else if (bid < 768) {
    int e = ((bid - 512) * 256 + t) * 8;  // W3 -> bf16 via cvt_pk
    float4 f0 = *(const float4*)(W3 + e);
    float4 f1 = *(const float4*)(W3 + e + 4);
    uint4 v;
    v.x = cvtpk_bf16(f0.x, f0.y);
    v.y = cvtpk_bf16(f0.z, f0.w);
    v.z = cvtpk_bf16(f1.x, f1.y);
    v.w = cvtpk_bf16(f1.z, f1.w);
    *(uint4*)(W3b + e) = v;
  } else if (bid < 1024) {
    int e = ((bid - 768) * 256 + t) * 8;  // W1 -> hi/lo fp16
    float ff[8];
    *(float4*)&ff[0] = *(const float4*)(W1 + e);
    *(float4*)&ff[4] = *(const float4*)(W1 + e + 4);
    ushort8 h, l;
#pragma unroll
    for (int i = 0; i < 8; i++) {
      unsigned short hi = f2h(ff[i]);
      h[i] = hi;
      l[i] = f2h(ff[i] - h2f(hi));
    }
    *(ushort8*)(w1h + e) = h;
    *(ushort8*)(w1l + e) = l;
  } else {
    int k = bid - 1024;  // const[k]
    float s = 0.f;
    for (int j = t; j < 4096; j += 256) s += W3[k * 4096 + j] * b2[j];
#pragma unroll
    for (int mk = 1; mk < 64; mk <<= 1) s += __shfl_xor(s, mk, 64);
    if ((t & 63) == 0) red[t >> 6] = s;
    __syncthreads();
    if (t == 0) constv[k] = red[0] + red[1] + red[2] + red[3] + b3[k];
  }
}

// ---------------------------------------------------------------------------
// k_fused: heterogeneous grid — blocks [0,512) run the r10 k1 body VERBATIM
// (harness-passed 3 rounds, 155 µs); blocks [512,768) run k2 reshaped to
// 512 threads (c-tile 128, 8 waves, jq = (bid-512)>>5). k1 and k2 are data-
// independent; k1 runs 2 blocks/CU with ~54% stall and <3% HBM use, so k2
// blocks co-resident as a 3rd block/CU (LDS 2*25.6+10.25=61KB) execute in
// k1's stall cycles — IF fused VGPR stays <=64 (waves/CU halves above 64).
// If VGPR lands in (64,128], k2 blocks queue behind k1 = today's serial
// behavior minus one launch (bounded downside).
// k2 numerics: same j-ordering, same per-chunk accumulation, same cvt_pk
// pack -> Mt bit-identical to r10.
// ---------------------------------------------------------------------------
__global__ __launch_bounds__(512, 4) void k_fused(
    const float* __restrict__ x, const unsigned short* __restrict__ w1h,
    const unsigned short* __restrict__ w1l, const float* __restrict__ b1,
    int* __restrict__ idxbuf, int* __restrict__ cntF, int* __restrict__ listF,
    int* __restrict__ cnt2, int2* __restrict__ list2,
    const float* __restrict__ W2, const unsigned short* __restrict__ W3b,
    float* __restrict__ Mt) {
  __shared__ __align__(16) char smem[25600];  // union: k1 25600 B / k2 10240 B
  const int bid = blockIdx.x;
  const int t = threadIdx.x;

  if (bid < 512) {
    // ================= k1 body (r10 verbatim) =================
    unsigned short* xsh = (unsigned short*)smem;      // [64*136] fp16 x tile
    uint2* wavebuf = (uint2*)(smem + 17408);          // [2][512] key pairs

    const int r0 = bid * 64;

    // ---- stage x rows 64x128 -> fp16 (once per block) ----
#pragma unroll
    for (int it = 0; it < 2; it++) {
      int ch = it * 512 + t;          // 1024 chunks of 8 elems
      int row = ch >> 4, k8 = ch & 15;
      float ff[8];
      *(float4*)&ff[0] = *(const float4*)(x + (r0 + row) * 128 + k8 * 8);
      *(float4*)&ff[4] = *(const float4*)(x + (r0 + row) * 128 + k8 * 8 + 4);
      ushort8 h;
#pragma unroll
      for (int i = 0; i < 8; i++) h[i] = f2h(ff[i]);
      *(ushort8*)&xsh[row * 136 + k8 * 8] = h;
    }
    __syncthreads();

    const int lane = t & 63, w = t >> 6;      // 8 waves
    const int m = lane & 15, q = lane >> 4;

#define AOFF(seg_, a_, ks_) ((size_t)(((seg_) * 256 + w * 32 + (a_) * 16 + m)) * 128 + (ks_) * 32 + q * 8)

    // prefetch seg 0, ks 0
    f16x8 pah[2], pal[2];
#pragma unroll
    for (int a = 0; a < 2; a++) {
      pah[a] = *(const f16x8*)(w1h + AOFF(0, a, 0));
      pal[a] = *(const f16x8*)(w1l + AOFF(0, a, 0));
    }

    for (int seg = 0; seg < 16; ++seg) {
      const int cb = seg * 256 + w * 32;      // wave's first seg-col

      f32x4 acc[2][4];
#pragma unroll
      for (int a = 0; a < 2; a++)
#pragma unroll
        for (int b = 0; b < 4; b++) acc[a][b] = (f32x4){0.f, 0.f, 0.f, 0.f};

      // bias loads issued early: L2 latency hides under the MFMA loop
      float4 bias4[2];
#pragma unroll
      for (int a = 0; a < 2; a++)
        bias4[a] = *(const float4*)&b1[cb + a * 16 + q * 4];

#pragma unroll
      for (int ks = 0; ks < 4; ks++) {
        const int k0 = ks * 32;
        f16x8 ah[2], al[2];
        if (ks == 0) {
          ah[0] = pah[0]; ah[1] = pah[1];
          al[0] = pal[0]; al[1] = pal[1];
        } else {
#pragma unroll
          for (int a = 0; a < 2; a++) {
            ah[a] = *(const f16x8*)(w1h + AOFF(seg, a, ks));
            al[a] = *(const f16x8*)(w1l + AOFF(seg, a, ks));
          }
        }
#pragma unroll
        for (int b = 0; b < 4; b++) {
          f16x8 bx = *(const f16x8*)&xsh[(b * 16 + m) * 136 + k0 + q * 8];
#pragma unroll
          for (int a = 0; a < 2; a++) {
            acc[a][b] = __builtin_amdgcn_mfma_f32_16x16x32_f16(ah[a], bx, acc[a][b], 0, 0, 0);
            acc[a][b] = __builtin_amdgcn_mfma_f32_16x16x32_f16(al[a], bx, acc[a][b], 0, 0, 0);
          }
        }
      }

      // prefetch next seg's ks=0 A-frags: latency hides under epilogue+merge
      if (seg + 1 < 16) {
#pragma unroll
        for (int a = 0; a < 2; a++) {
          pah[a] = *(const f16x8*)(w1h + AOFF(seg + 1, a, 0));
          pal[a] = *(const f16x8*)(w1l + AOFF(seg + 1, a, 0));
        }
      }

      // ---- epilogue: per-row top-2 keys (proven math) ----
#pragma unroll
      for (int b = 0; b < 4; b++) {
        unsigned int K1 = 0u, K2 = 0u;
#pragma unroll
        for (int a = 0; a < 2; a++)
#pragma unroll
          for (int r = 0; r < 4; r++) {
            float v = acc[a][b][r] + bias4[a][r];
            unsigned int col = (unsigned)(w * 32 + a * 16 + q * 4 + r);
            unsigned int key = (f2ord(v) & 0xFFFFFF00u) | (255u - col);
            unsigned int mx = K1 > key ? K1 : key;
            unsigned int mn = K1 > key ? key : K1;
            K1 = mx; K2 = K2 > mn ? K2 : mn;
          }
#pragma unroll
        for (int msk = 16; msk <= 32; msk <<= 1) {
          unsigned int p1 = (unsigned int)__shfl_xor((int)K1, msk, 64);
          unsigned int p2 = (unsigned int)__shfl_xor((int)K2, msk, 64);
          unsigned int mx = K1 > p1 ? K1 : p1;
          unsigned int mn = K1 > p1 ? p1 : K1;
          unsigned int sel = K1 >= p1 ? K2 : p2;
          K1 = mx;
          K2 = sel > mn ? sel : mn;
        }
        if (lane < 16) {  // q == 0
          uint2 pr; pr.x = K1; pr.y = K2;
          wavebuf[(seg & 1) * 512 + w * 64 + b * 16 + m] = pr;
        }
      }

      barrier_lgkm();  // wavebuf[seg&1] visible; globals stay in flight

      // ---- distributed merge + two-tier classification (lane<8 per wave) ----
      if (lane < 8) {
        const int row = w * 8 + lane;
        unsigned int K1 = 0u, K2 = 0u, K3 = 0u;
#pragma unroll
        for (int wp = 0; wp < 8; wp++) {
          uint2 pr = wavebuf[(seg & 1) * 512 + wp * 64 + row];
          unsigned int v0 = pr.x;
          unsigned int t1 = K1 > v0 ? K1 : v0, b1_ = K1 > v0 ? v0 : K1;
          unsigned int t2 = K2 > b1_ ? K2 : b1_, b2_ = K2 > b1_ ? b1_ : K2;
          K1 = t1; K2 = t2; K3 = K3 > b2_ ? K3 : b2_;
          v0 = pr.y;
          t1 = K1 > v0 ? K1 : v0; b1_ = K1 > v0 ? v0 : K1;
          t2 = K2 > b1_ ? K2 : b1_; b2_ = K2 > b1_ ? b1_ : K2;
          K1 = t1; K2 = t2; K3 = K3 > b2_ ? K3 : b2_;
        }
        int colw = 255 - (int)(K1 & 255u);
        int col2 = 255 - (int)(K2 & 255u);
        int bgl = r0 + row;
        idxbuf[bgl * 16 + seg] = colw;
        float v1 = ord2f(K1 & 0xFFFFFF00u);
        float v2 = ord2f(K2 & 0xFFFFFF00u);
        float v3 = ord2f(K3 & 0xFFFFFF00u);
        if (v1 - v2 < MARGIN2F) {
          int pk = (bgl << 4) | seg;
          bool full = ((colw >> 5) == (col2 >> 5)) || (v1 - v3 < MARGIN2F);
          if (full) {
            int p = atomicAdd(cntF, 1);
            if (p < CAPF) listF[p] = pk;
          } else {
            int p = atomicAdd(cnt2, 1);
            if (p < CAP2) {
              list2[p] = (int2){pk, (colw << 8) | col2};
            } else {  // overflow: full fix is a correct superset handler
              int pf = atomicAdd(cntF, 1);
              if (pf < CAPF) listF[pf] = pk;
            }
          }
        }
      }
      // next seg writes wavebuf[(seg+1)&1] -> no second barrier needed
    }
#undef AOFF
  } else {
    // ================= k2 body (512-thread reshape of r10) =================
    unsigned short* ldsT = (unsigned short*)smem;     // [128][40] shorts
    const int kb = bid - 512;
    const int c0 = (kb & 31) * 128;                   // 32 c-tiles of 128
    const int jq = kb >> 5;                           // 8 K-chunks of 512
    const int lane = t & 63, wv = t >> 6;             // 8 waves, 16 cols each
    const int m = lane & 15, q = lane >> 4;
    const int jp = t >> 5, cq = t & 31;               // j-pair, c-quad

    f32x4 acc[8];
#pragma unroll
    for (int nt = 0; nt < 8; nt++) acc[nt] = (f32x4){0.f, 0.f, 0.f, 0.f};

    // preload it=0 (two adjacent j-rows, same c-quad)
    float4 pA = *(const float4*)&W2[(size_t)(jq * 512 + 2 * jp) * 4096 + c0 + cq * 4];
    float4 pB = *(const float4*)&W2[(size_t)(jq * 512 + 2 * jp + 1) * 4096 + c0 + cq * 4];

    for (int it = 0; it < 16; it++) {
      const int j0 = jq * 512 + it * 32;
      unsigned int d0 = cvtpk_bf16(pA.x, pB.x);
      unsigned int d1 = cvtpk_bf16(pA.y, pB.y);
      unsigned int d2 = cvtpk_bf16(pA.z, pB.z);
      unsigned int d3 = cvtpk_bf16(pA.w, pB.w);
      *(unsigned int*)&ldsT[(cq * 4 + 0) * 40 + jp * 2] = d0;
      *(unsigned int*)&ldsT[(cq * 4 + 1) * 40 + jp * 2] = d1;
      *(unsigned int*)&ldsT[(cq * 4 + 2) * 40 + jp * 2] = d2;
      *(unsigned int*)&ldsT[(cq * 4 + 3) * 40 + jp * 2] = d3;
      barrier_lgkm();
      bf16x8 av = *(const bf16x8*)&ldsT[(wv * 16 + m) * 40 + q * 8];
      // prefetch next iter while MFMA phase runs
      if (it + 1 < 16) {
        const int jn = j0 + 32;
        pA = *(const float4*)&W2[(size_t)(jn + 2 * jp) * 4096 + c0 + cq * 4];
        pB = *(const float4*)&W2[(size_t)(jn + 2 * jp + 1) * 4096 + c0 + cq * 4];
      }
#pragma unroll
      for (int nt = 0; nt < 8; nt++) {
        bf16x8 b = *(const bf16x8*)(W3b + (nt * 16 + m) * 4096 + j0 + q * 8);
        acc[nt] = __builtin_amdgcn_mfma_f32_16x16x32_bf16(av, b, acc[nt], 0, 0, 0);
      }
      barrier_lgkm();  // av reads drained; ldsT safe to overwrite next iter
    }
#pragma unroll
    for (int nt = 0; nt < 8; nt++)
#pragma unroll
      for (int r = 0; r < 4; r++)
        atomicAdd(&Mt[(size_t)(c0 + wv * 16 + q * 4 + r) * 128 + nt * 16 + m], acc[nt][r]);
  }
}

// ---------------------------------------------------------------------------
// K1fix (r9/r10, harness-passed): full 256-col exact recompute + 2-col exact
// compare. UNCHANGED.
// ---------------------------------------------------------------------------
__global__ __launch_bounds__(256) void k1_fix(
    const float* __restrict__ x, const float* __restrict__ W1,
    const float* __restrict__ b1,
    const int* __restrict__ cntF, const int* __restrict__ listF,
    const int* __restrict__ cnt2, const int2* __restrict__ list2,
    int* __restrict__ idxbuf) {
  __shared__ float redv[4];
  __shared__ int   redi[4];
  const int t = threadIdx.x;
  const int lane = t & 63, wv = t >> 6;

  // ---- phase 1: full fixups ----
  int nf = cntF[0]; if (nf > CAPF) nf = CAPF;
  for (int e = blockIdx.x; e < nf; e += gridDim.x) {
    int pk = listF[e];
    int b = pk >> 4, seg = pk & 15;
    int c = seg * 256 + t;
    float a = b1[c];
    const float4* xr = (const float4*)(x + (size_t)b * 128);
    const float4* wr = (const float4*)(W1 + (size_t)c * 128);
#pragma unroll 8
    for (int k4 = 0; k4 < 32; k4++) {
      float4 xv = xr[k4];
      float4 wv4 = wr[k4];
      a = fmaf(xv.x, wv4.x, a);
      a = fmaf(xv.y, wv4.y, a);
      a = fmaf(xv.z, wv4.z, a);
      a = fmaf(xv.w, wv4.w, a);
    }
    float v = a; int li = t;
#pragma unroll
    for (int msk = 1; msk < 64; msk <<= 1) {
      float u = __shfl_xor(v, msk, 64);
      int ju = __shfl_xor(li, msk, 64);
      if (u > v || (u == v && ju < li)) { v = u; li = ju; }
    }
    if (lane == 0) { redv[wv] = v; redi[wv] = li; }
    __syncthreads();
    if (t == 0) {
      float bv = redv[0]; int bi = redi[0];
#pragma unroll
      for (int w = 1; w < 4; w++) {
        if (redv[w] > bv || (redv[w] == bv && redi[w] < bi)) { bv = redv[w]; bi = redi[w]; }
      }
      idxbuf[b * 16 + seg] = bi;
    }
    __syncthreads();
  }

  // ---- phase 2: 2-col fixups (one per thread) ----
  int n2 = cnt2[0]; if (n2 > CAP2) n2 = CAP2;
  for (int e = blockIdx.x * 256 + t; e < n2; e += gridDim.x * 256) {
    int2 en = list2[e];
    int pk = en.x;
    int b = pk >> 4, seg = pk & 15;
    int i1 = (en.y >> 8) & 255, i2 = en.y & 255;
    int c1 = seg * 256 + i1, c2 = seg * 256 + i2;
    const float* xr = x + (size_t)b * 128;
    const float* w1r = W1 + (size_t)c1 * 128;
    const float* w2r = W1 + (size_t)c2 * 128;
    float a1 = b1[c1], a2 = b1[c2];
#pragma unroll 16
    for (int k = 0; k < 128; k++) {
      float xv = xr[k];
      a1 = fmaf(xv, w1r[k], a1);
      a2 = fmaf(xv, w2r[k], a2);
    }
    int win = (a1 > a2) ? i1 : (a2 > a1) ? i2 : (i1 < i2 ? i1 : i2);
    idxbuf[b * 16 + seg] = win;
  }
}

// ---------------------------------------------------------------------------
// K3: out[b,k] = const[k] + sum_g Mt[g*256 + idx[b,g], k]  (unchanged)
// ---------------------------------------------------------------------------
__global__ __launch_bounds__(256) void k3_gather(const int* __restrict__ idxbuf,
                                                 const float* __restrict__ Mt,
                                                 const float* __restrict__ constv,
                                                 float* __restrict__ out) {
  const int t = threadIdx.x;
  const int w = t >> 6;
  const int lane = t & 63;
  const int b = blockIdx.x * 4 + w;
  float a0 = constv[lane];
  float a1 = constv[lane + 64];
  const int* ib = idxbuf + b * 16;
  int cg[16];
#pragma unroll
  for (int g = 0; g < 16; g++) cg[g] = g * 256 + ib[g];
#pragma unroll
  for (int g = 0; g < 16; g++) {
    const float* mrow = Mt + (size_t)cg[g] * 128;
    a0 += mrow[lane];
    a1 += mrow[lane + 64];
  }
  out[b * 128 + lane] = a0;
  out[b * 128 + lane + 64] = a1;
}

// ---------------------------------------------------------------------------
extern "C" void kernel_launch(void* const* d_in, const int* in_sizes, int n_in,
                              void* d_out, int out_size, void* d_ws, size_t ws_size,
                              hipStream_t stream) {
  const float* x  = (const float*)d_in[0];
  const float* W1 = (const float*)d_in[1];
  const float* b1 = (const float*)d_in[2];
  const float* W2 = (const float*)d_in[3];
  const float* b2 = (const float*)d_in[4];
  const float* W3 = (const float*)d_in[5];
  const float* b3 = (const float*)d_in[6];
  float* out = (float*)d_out;

  char* w = (char*)d_ws;
  int* idxbuf         = (int*)(w);                              // 2 MB
  unsigned short* W3b = (unsigned short*)(w + (2u << 20));      // 1 MB
  float* Mt           = (float*)(w + (3u << 20));               // 2 MB
  unsigned short* w1h = (unsigned short*)(w + (5u << 20));      // 1 MB (fp16 hi)
  unsigned short* w1l = (unsigned short*)(w + (6u << 20));      // 1 MB (fp16 lo)
  float* constv       = (float*)(w + (7u << 20));               // 512 B
  int* cntF           = (int*)(w + (7u << 20) + 1024);          // 4 B
  int* cnt2           = (int*)(w + (7u << 20) + 1280);          // 4 B (own line)
  int* listF          = (int*)(w + (7u << 20) + 4096);          // 128 KB
  int2* list2         = (int2*)(w + (7u << 20) + 139264);       // 256 KB

  kprep<<<1152, 256, 0, stream>>>(Mt, cntF, cnt2, W3, W3b, W1, w1h, w1l, b2, b3, constv);
  k_fused<<<768, 512, 0, stream>>>(x, w1h, w1l, b1, idxbuf, cntF, listF, cnt2, list2,
                                   W2, W3b, Mt);
  k1_fix<<<2048, 256, 0, stream>>>(x, W1, b1, cntF, listF, cnt2, list2, idxbuf);
  k3_gather<<<8192, 256, 0, stream>>>(idxbuf, Mt, constv, out);
}